// Round 2
// baseline (137.638 us; speedup 1.0000x reference)
//
#include <hip/hip_runtime.h>
#include <hip/hip_bf16.h>

#define B 8
#define N 1024
#define IN 256
#define H 4
#define D 64
#define O 256   // H*D
#define BN (B*N)
#define LOG2E 1.4426950408889634f

typedef __attribute__((ext_vector_type(4))) float f32x4;
typedef __attribute__((ext_vector_type(8))) short short8;
typedef __attribute__((ext_vector_type(4))) short short4v;

__device__ __forceinline__ short f2bf(float f){
  __hip_bfloat16 b = __float2bfloat16(f);
  return __builtin_bit_cast(short, b);
}

__device__ __forceinline__ short8 pack8(float4 a0, float4 a1){
  short8 pk;
  pk[0]=f2bf(a0.x); pk[1]=f2bf(a0.y); pk[2]=f2bf(a0.z); pk[3]=f2bf(a0.w);
  pk[4]=f2bf(a1.x); pk[5]=f2bf(a1.y); pk[6]=f2bf(a1.z); pk[7]=f2bf(a1.w);
  return pk;
}

// ---------------------------------------------------------------------------
// k1 (fused): blocks [0, WH_BLOCKS) do Wh = h @ W^T with inline fp32->bf16
// conversion (h is read exactly once -> pre-converting was wasted traffic),
// writing VT[b][h][d][n] bf16 + src/dst (scaled by log2e for native exp2 in
// k_attn). Blocks [WH_BLOCKS, +PACK_BLOCKS) pack adj int32 -> bitmask words.
// The two halves touch disjoint data; the BW-bound pack overlaps the
// latency-bound GEMM.
// ---------------------------------------------------------------------------
#define WH_BLOCKS  (BN/16)    // 512
#define PACK_BLOCKS 1024

__global__ __launch_bounds__(256) void k1(const int* __restrict__ adj,
                                          unsigned* __restrict__ bits,
                                          const float* __restrict__ hmat,
                                          const float* __restrict__ Wmat,
                                          const float* __restrict__ avec,
                                          short* __restrict__ VT,
                                          float* __restrict__ src,
                                          float* __restrict__ dst){
  if(blockIdx.x >= WH_BLOCKS){
    // ---- adj bit-pack: one 32-bit word per thread ----
    int t = (blockIdx.x - WH_BLOCKS) * 256 + threadIdx.x;     // [0, 262144)
    const int4* p = (const int4*)(adj + ((size_t)t << 5));
    unsigned word = 0;
    #pragma unroll
    for(int k = 0; k < 8; k++){
      int4 m = p[k];
      word |= (m.x != 0 ? 1u : 0u) << (k*4 + 0);
      word |= (m.y != 0 ? 1u : 0u) << (k*4 + 1);
      word |= (m.z != 0 ? 1u : 0u) << (k*4 + 2);
      word |= (m.w != 0 ? 1u : 0u) << (k*4 + 3);
    }
    bits[t] = word;
    return;
  }
  // ---- Wh GEMM: 16 rows x 256 cols per block, fp32 inputs converted inline ----
  const int t = threadIdx.x;
  const int hh = t >> 6, lane = t & 63, quad = lane >> 4, l16 = lane & 15;
  const int mbase = blockIdx.x * 16;
  f32x4 acc[4];
  #pragma unroll
  for(int x=0;x<4;x++) acc[x] = (f32x4){0.f,0.f,0.f,0.f};
  const float* ap  = hmat + (size_t)(mbase + l16) * IN + quad * 8;
  const float* bp0 = Wmat + (size_t)(hh * 64 + l16) * IN + quad * 8;
  #pragma unroll
  for(int kk = 0; kk < 8; kk++){
    const int k0 = kk * 32;
    float4 a0 = *(const float4*)(ap + k0);
    float4 a1 = *(const float4*)(ap + k0 + 4);
    short8 A = pack8(a0, a1);
    #pragma unroll
    for(int dt=0; dt<4; dt++){
      const float* bp = bp0 + (size_t)dt*16*IN + k0;
      float4 b0 = *(const float4*)bp;
      float4 b1 = *(const float4*)(bp + 4);
      short8 Bf = pack8(b0, b1);
      acc[dt] = __builtin_amdgcn_mfma_f32_16x16x32_bf16(A, Bf, acc[dt], 0, 0, 0);
    }
  }
  const int bb = mbase >> 10;
  const int nb = (mbase & (N-1)) + quad * 4;
  const int bh = bb * H + hh;
  #pragma unroll
  for(int dt=0; dt<4; dt++){
    int d = dt*16 + l16;
    short4v pk;
    pk[0]=f2bf(acc[dt][0]); pk[1]=f2bf(acc[dt][1]);
    pk[2]=f2bf(acc[dt][2]); pk[3]=f2bf(acc[dt][3]);
    *(short4v*)(VT + (((size_t)bh * D + d) << 10) + nb) = pk;
  }
  float as[4], ad[4];
  #pragma unroll
  for(int dt=0; dt<4; dt++){
    as[dt] = avec[hh*(2*D) + dt*16 + l16];
    ad[dt] = avec[hh*(2*D) + D + dt*16 + l16];
  }
  #pragma unroll
  for(int r=0; r<4; r++){
    float s = 0.f, dd = 0.f;
    #pragma unroll
    for(int dt=0; dt<4; dt++){ s += acc[dt][r]*as[dt]; dd += acc[dt][r]*ad[dt]; }
    #pragma unroll
    for(int off=1; off<16; off<<=1){
      s  += __shfl_xor(s, off, 64);
      dd += __shfl_xor(dd, off, 64);
    }
    if(l16 == 0){
      int n = nb + r;
      // pre-scale by log2(e): leaky_relu is positively homogeneous, so
      // exp(leaky(s+d)) == exp2(leaky((s+d)*log2e))
      src[(size_t)bh * N + n] = s  * LOG2E;
      dst[(size_t)bh * N + n] = dd * LOG2E;
    }
  }
}

// ---------------------------------------------------------------------------
// k_attn: masked softmax + PV. Register-slimmed vs prior version:
//  - mask words stream as ping-pong int4 groups (8 VGPR, was 32)
//  - VT B-fragments double-buffered with named bufA/bufB (static indexing
//    guaranteed; was %3 rotation over 48 VGPR)
//  - dsh float4s prefetched one step ahead
//  - __launch_bounds__(256,2): grid is 512 blocks = 2 blocks/CU, so the old
//    (256,4) 128-VGPR cap bought nothing and risked spills.
// Row sums via extra MFMA against ones-fragment. One barrier total.
// ---------------------------------------------------------------------------
__global__ __launch_bounds__(256, 2) void k_attn(const short* __restrict__ VT,
                                                 const float* __restrict__ src,
                                                 const float* __restrict__ dst,
                                                 const unsigned* __restrict__ bits,
                                                 float* __restrict__ out){
  __shared__ float dsh[N];
  const int t = threadIdx.x;
  const int wave = t >> 6, lane = t & 63, quad = lane >> 4, l16 = lane & 15;
  const int b = blockIdx.z, hh = blockIdx.y;
  const int bh = b * H + hh;
  const int i0 = blockIdx.x * 64;
  #pragma unroll
  for(int j = t; j < N; j += 256) dsh[j] = dst[(size_t)bh * N + j];
  const int i = i0 + wave * 16 + l16;
  const float si = src[(size_t)bh * N + i];
  const int4* mp = (const int4*)(bits + ((size_t)b * N + i) * 32);
  int4 mcur = mp[0];
  int4 mnext = mp[1];
  const short* vrow = VT + (((size_t)bh * D) << 10) + quad * 8;
  short8 ones;
  #pragma unroll
  for(int k=0;k<8;k++) ones[k] = (short)0x3F80;   // bf16 1.0
  f32x4 acc[4], accl;
  #pragma unroll
  for(int x=0;x<4;x++) acc[x] = (f32x4){0.f,0.f,0.f,0.f};
  accl = (f32x4){0.f,0.f,0.f,0.f};
  short8 bufA[4], bufB[4];
  #pragma unroll
  for(int dt=0; dt<4; dt++)
    bufA[dt] = *(const short8*)(vrow + (((size_t)(dt*16 + l16)) << 10));
  __syncthreads();
  float4 dA0 = *(const float4*)&dsh[quad*8];
  float4 dA1 = *(const float4*)&dsh[quad*8 + 4];
  float4 dB0, dB1;

#define STEP(JT, BC, BNX, DC0, DC1, DN0, DN1, WORD) do {                        \
    if((JT) < 31){                                                              \
      _Pragma("unroll")                                                         \
      for(int dt=0; dt<4; dt++)                                                 \
        BNX[dt] = *(const short8*)(vrow + (((size_t)(dt*16 + l16)) << 10)       \
                                   + ((JT)+1)*32);                              \
      DN0 = *(const float4*)&dsh[((JT)+1)*32 + quad*8];                         \
      DN1 = *(const float4*)&dsh[((JT)+1)*32 + quad*8 + 4];                     \
    }                                                                           \
    const unsigned wsh = ((unsigned)(WORD)) >> (quad*8);                        \
    float dvv[8] = {DC0.x,DC0.y,DC0.z,DC0.w,DC1.x,DC1.y,DC1.z,DC1.w};           \
    short8 P;                                                                   \
    _Pragma("unroll")                                                           \
    for(int jj=0; jj<8; jj++){                                                  \
      float e = si + dvv[jj];                                                   \
      float l = fmaxf(e, 0.2f * e);            /* leaky_relu in log2 domain */  \
      float p = ((wsh >> jj) & 1u) ? __builtin_exp2f(l) : 0.f;                  \
      P[jj] = f2bf(p);                                                          \
    }                                                                           \
    accl = __builtin_amdgcn_mfma_f32_16x16x32_bf16(P, ones, accl, 0, 0, 0);     \
    _Pragma("unroll")                                                           \
    for(int dt=0; dt<4; dt++)                                                   \
      acc[dt] = __builtin_amdgcn_mfma_f32_16x16x32_bf16(P, BC[dt], acc[dt],     \
                                                        0, 0, 0);               \
  } while(0)

  for(int g = 0; g < 8; ++g){
    const int jt0 = g * 4;
    STEP(jt0+0, bufA, bufB, dA0, dA1, dB0, dB1, mcur.x);
    STEP(jt0+1, bufB, bufA, dB0, dB1, dA0, dA1, mcur.y);
    STEP(jt0+2, bufA, bufB, dA0, dA1, dB0, dB1, mcur.z);
    STEP(jt0+3, bufB, bufA, dB0, dB1, dA0, dA1, mcur.w);
    mcur = mnext;
    if(g < 6) mnext = mp[g + 2];
  }
#undef STEP

  // epilogue: C row = quad*4+r, col = l16; accl[r] is that row's sum.
  #pragma unroll
  for(int r=0; r<4; r++){
    float inv = 1.0f / accl[r];
    int ig = i0 + wave*16 + quad*4 + r;
    float* op = out + ((size_t)b * N + ig) * O + hh * D + l16;
    #pragma unroll
    for(int dt=0; dt<4; dt++) op[dt*16] = acc[dt][r] * inv;
  }
}

extern "C" void kernel_launch(void* const* d_in, const int* in_sizes, int n_in,
                              void* d_out, int out_size, void* d_ws, size_t ws_size,
                              hipStream_t stream) {
  const float* hmat = (const float*)d_in[0];
  const float* Wmat = (const float*)d_in[1];
  const float* avec = (const float*)d_in[2];
  const int* adj    = (const int*)d_in[3];   // numpy bool -> int32 per harness
  float* out = (float*)d_out;
  char* ws = (char*)d_ws;
  short*    VT   = (short*)   (ws);                          // 4 MB
  unsigned* bits = (unsigned*)(ws + (size_t)4*1024*1024);    // 1 MB
  float*    src  = (float*)   (ws + (size_t)5*1024*1024);    // 128 KB
  float*    dst  = (float*)   (ws + (size_t)5*1024*1024 + 131072);
  k1<<<WH_BLOCKS + PACK_BLOCKS, 256, 0, stream>>>(adj, bits, hmat, Wmat, avec, VT, src, dst);
  k_attn<<<dim3(16, H, B), 256, 0, stream>>>(VT, src, dst, bits, out);
}

// Round 4
// 132.682 us; speedup vs baseline: 1.0374x; 1.0374x over previous
//
#include <hip/hip_runtime.h>
#include <hip/hip_bf16.h>

#define B 8
#define N 1024
#define IN 256
#define H 4
#define D 64
#define O 256   // H*D
#define BN (B*N)
#define LOG2E 1.4426950408889634f

typedef __attribute__((ext_vector_type(4))) float f32x4;
typedef __attribute__((ext_vector_type(8))) short short8;
typedef __attribute__((ext_vector_type(4))) short short4v;

__device__ __forceinline__ short f2bf(float f){
  __hip_bfloat16 b = __float2bfloat16(f);
  return __builtin_bit_cast(short, b);
}

__device__ __forceinline__ short8 pack8(float4 a0, float4 a1){
  short8 pk;
  pk[0]=f2bf(a0.x); pk[1]=f2bf(a0.y); pk[2]=f2bf(a0.z); pk[3]=f2bf(a0.w);
  pk[4]=f2bf(a1.x); pk[5]=f2bf(a1.y); pk[6]=f2bf(a1.z); pk[7]=f2bf(a1.w);
  return pk;
}

// ---------------------------------------------------------------------------
// k_prep: (a) pack adj int32 -> bitmask words (33.5 MB read, BW-bound,
// irreducible single pass)  (b) convert W fp32 -> bf16 (132 KB, one-shot).
// h is NOT pre-converted: it is read exactly once by the GEMM, which converts
// it inline on the A side (once-cost). W must be pre-converted because every
// GEMM block would otherwise re-convert the full 256x256 W (512x redundant
// VALU — the measured Round-2 regression).
// ---------------------------------------------------------------------------
#define PACK_BLOCKS 1024
#define WCVT_BLOCKS 32          // 32*256*8 = 65536 = IN*O elements

__global__ __launch_bounds__(256) void k_prep(const int* __restrict__ adj,
                                              unsigned* __restrict__ bits,
                                              const float* __restrict__ Wmat,
                                              short* __restrict__ wbf){
  if(blockIdx.x < PACK_BLOCKS){
    int t = blockIdx.x * 256 + threadIdx.x;          // [0, 262144)
    const int4* p = (const int4*)(adj + ((size_t)t << 5));
    unsigned word = 0;
    #pragma unroll
    for(int k = 0; k < 8; k++){
      int4 m = p[k];
      word |= (m.x != 0 ? 1u : 0u) << (k*4 + 0);
      word |= (m.y != 0 ? 1u : 0u) << (k*4 + 1);
      word |= (m.z != 0 ? 1u : 0u) << (k*4 + 2);
      word |= (m.w != 0 ? 1u : 0u) << (k*4 + 3);
    }
    bits[t] = word;
  } else {
    int e = ((blockIdx.x - PACK_BLOCKS) * 256 + threadIdx.x) * 8;  // [0, 65536)
    float4 a0 = *(const float4*)(Wmat + e);
    float4 a1 = *(const float4*)(Wmat + e + 4);
    *(short8*)(wbf + e) = pack8(a0, a1);
  }
}

// ---------------------------------------------------------------------------
// k_wh: Wh = h @ W^T. A side: fp32 h converted inline (each element converted
// exactly once per block — no redundancy). B side: pre-converted bf16 W.
// Writes VT[b][h][d][n] (bf16) + fused src/dst epilogue (scaled by log2e so
// k_attn uses native exp2).
// ---------------------------------------------------------------------------
__global__ __launch_bounds__(256) void k_wh(const float* __restrict__ hmat,
                                            const short* __restrict__ wbf,
                                            const float* __restrict__ avec,
                                            short* __restrict__ VT,
                                            float* __restrict__ src,
                                            float* __restrict__ dst){
  const int t = threadIdx.x;
  const int hh = t >> 6, lane = t & 63, quad = lane >> 4, l16 = lane & 15;
  const int mbase = blockIdx.x * 16;
  f32x4 acc[4];
  #pragma unroll
  for(int x=0;x<4;x++) acc[x] = (f32x4){0.f,0.f,0.f,0.f};
  const float* ap  = hmat + (size_t)(mbase + l16) * IN + quad * 8;
  const short* bp0 = wbf  + (size_t)(hh * 64 + l16) * IN + quad * 8;
  #pragma unroll
  for(int kk = 0; kk < 8; kk++){
    const int k0 = kk * 32;
    float4 a0 = *(const float4*)(ap + k0);
    float4 a1 = *(const float4*)(ap + k0 + 4);
    short8 A = pack8(a0, a1);
    #pragma unroll
    for(int dt=0; dt<4; dt++){
      short8 Bf = *(const short8*)(bp0 + (size_t)dt*16*IN + k0);
      acc[dt] = __builtin_amdgcn_mfma_f32_16x16x32_bf16(A, Bf, acc[dt], 0, 0, 0);
    }
  }
  const int bb = mbase >> 10;
  const int nb = (mbase & (N-1)) + quad * 4;
  const int bh = bb * H + hh;
  #pragma unroll
  for(int dt=0; dt<4; dt++){
    int d = dt*16 + l16;
    short4v pk;
    pk[0]=f2bf(acc[dt][0]); pk[1]=f2bf(acc[dt][1]);
    pk[2]=f2bf(acc[dt][2]); pk[3]=f2bf(acc[dt][3]);
    *(short4v*)(VT + (((size_t)bh * D + d) << 10) + nb) = pk;
  }
  float as[4], ad[4];
  #pragma unroll
  for(int dt=0; dt<4; dt++){
    as[dt] = avec[hh*(2*D) + dt*16 + l16];
    ad[dt] = avec[hh*(2*D) + D + dt*16 + l16];
  }
  #pragma unroll
  for(int r=0; r<4; r++){
    float s = 0.f, dd = 0.f;
    #pragma unroll
    for(int dt=0; dt<4; dt++){ s += acc[dt][r]*as[dt]; dd += acc[dt][r]*ad[dt]; }
    #pragma unroll
    for(int off=1; off<16; off<<=1){
      s  += __shfl_xor(s, off, 64);
      dd += __shfl_xor(dd, off, 64);
    }
    if(l16 == 0){
      int n = nb + r;
      // pre-scale by log2(e): leaky_relu is positively homogeneous, so
      // exp(leaky(s+d)) == exp2(leaky((s+d)*log2e))
      src[(size_t)bh * N + n] = s  * LOG2E;
      dst[(size_t)bh * N + n] = dd * LOG2E;
    }
  }
}

// ---------------------------------------------------------------------------
// k_attn: masked softmax + PV. Register-slim version (passed Round 2):
//  - mask words stream as ping-pong int4 groups (8 VGPR)
//  - VT B-fragments double-buffered with named bufA/bufB (static indexing)
//  - dsh float4s prefetched one step ahead
//  - __launch_bounds__(256,2): grid = 512 blocks = 2 blocks/CU (grid-limited)
// Row sums via extra MFMA against ones-fragment. One barrier total.
// ---------------------------------------------------------------------------
__global__ __launch_bounds__(256, 2) void k_attn(const short* __restrict__ VT,
                                                 const float* __restrict__ src,
                                                 const float* __restrict__ dst,
                                                 const unsigned* __restrict__ bits,
                                                 float* __restrict__ out){
  __shared__ float dsh[N];
  const int t = threadIdx.x;
  const int wave = t >> 6, lane = t & 63, quad = lane >> 4, l16 = lane & 15;
  const int b = blockIdx.z, hh = blockIdx.y;
  const int bh = b * H + hh;
  const int i0 = blockIdx.x * 64;
  #pragma unroll
  for(int j = t; j < N; j += 256) dsh[j] = dst[(size_t)bh * N + j];
  const int i = i0 + wave * 16 + l16;
  const float si = src[(size_t)bh * N + i];
  const int4* mp = (const int4*)(bits + ((size_t)b * N + i) * 32);
  int4 mcur = mp[0];
  int4 mnext = mp[1];
  const short* vrow = VT + (((size_t)bh * D) << 10) + quad * 8;
  short8 ones;
  #pragma unroll
  for(int k=0;k<8;k++) ones[k] = (short)0x3F80;   // bf16 1.0
  f32x4 acc[4], accl;
  #pragma unroll
  for(int x=0;x<4;x++) acc[x] = (f32x4){0.f,0.f,0.f,0.f};
  accl = (f32x4){0.f,0.f,0.f,0.f};
  short8 bufA[4], bufB[4];
  #pragma unroll
  for(int dt=0; dt<4; dt++)
    bufA[dt] = *(const short8*)(vrow + (((size_t)(dt*16 + l16)) << 10));
  __syncthreads();
  float4 dA0 = *(const float4*)&dsh[quad*8];
  float4 dA1 = *(const float4*)&dsh[quad*8 + 4];
  float4 dB0, dB1;

#define STEP(JT, BC, BNX, DC0, DC1, DN0, DN1, WORD) do {                        \
    if((JT) < 31){                                                              \
      _Pragma("unroll")                                                         \
      for(int dt=0; dt<4; dt++)                                                 \
        BNX[dt] = *(const short8*)(vrow + (((size_t)(dt*16 + l16)) << 10)       \
                                   + ((JT)+1)*32);                              \
      DN0 = *(const float4*)&dsh[((JT)+1)*32 + quad*8];                         \
      DN1 = *(const float4*)&dsh[((JT)+1)*32 + quad*8 + 4];                     \
    }                                                                           \
    const unsigned wsh = ((unsigned)(WORD)) >> (quad*8);                        \
    float dvv[8] = {DC0.x,DC0.y,DC0.z,DC0.w,DC1.x,DC1.y,DC1.z,DC1.w};           \
    short8 P;                                                                   \
    _Pragma("unroll")                                                           \
    for(int jj=0; jj<8; jj++){                                                  \
      float e = si + dvv[jj];                                                   \
      float l = fmaxf(e, 0.2f * e);            /* leaky_relu in log2 domain */  \
      float p = ((wsh >> jj) & 1u) ? __builtin_exp2f(l) : 0.f;                  \
      P[jj] = f2bf(p);                                                          \
    }                                                                           \
    accl = __builtin_amdgcn_mfma_f32_16x16x32_bf16(P, ones, accl, 0, 0, 0);     \
    _Pragma("unroll")                                                           \
    for(int dt=0; dt<4; dt++)                                                   \
      acc[dt] = __builtin_amdgcn_mfma_f32_16x16x32_bf16(P, BC[dt], acc[dt],     \
                                                        0, 0, 0);               \
  } while(0)

  for(int g = 0; g < 8; ++g){
    const int jt0 = g * 4;
    STEP(jt0+0, bufA, bufB, dA0, dA1, dB0, dB1, mcur.x);
    STEP(jt0+1, bufB, bufA, dB0, dB1, dA0, dA1, mcur.y);
    STEP(jt0+2, bufA, bufB, dA0, dA1, dB0, dB1, mcur.z);
    STEP(jt0+3, bufB, bufA, dB0, dB1, dA0, dA1, mcur.w);
    mcur = mnext;
    if(g < 6) mnext = mp[g + 2];
  }
#undef STEP

  // epilogue: C row = quad*4+r, col = l16; accl[r] is that row's sum.
  #pragma unroll
  for(int r=0; r<4; r++){
    float inv = 1.0f / accl[r];
    int ig = i0 + wave*16 + quad*4 + r;
    float* op = out + ((size_t)b * N + ig) * O + hh * D + l16;
    #pragma unroll
    for(int dt=0; dt<4; dt++) op[dt*16] = acc[dt][r] * inv;
  }
}

extern "C" void kernel_launch(void* const* d_in, const int* in_sizes, int n_in,
                              void* d_out, int out_size, void* d_ws, size_t ws_size,
                              hipStream_t stream) {
  const float* hmat = (const float*)d_in[0];
  const float* Wmat = (const float*)d_in[1];
  const float* avec = (const float*)d_in[2];
  const int* adj    = (const int*)d_in[3];   // numpy bool -> int32 per harness
  float* out = (float*)d_out;
  char* ws = (char*)d_ws;
  short*    VT   = (short*)   (ws);                          // 4 MB
  short*    wbf  = (short*)   (ws + (size_t)4*1024*1024);    // 128 KB
  unsigned* bits = (unsigned*)(ws + (size_t)5*1024*1024);    // 1 MB
  float*    src  = (float*)   (ws + (size_t)6*1024*1024);    // 128 KB
  float*    dst  = (float*)   (ws + (size_t)6*1024*1024 + 131072);
  k_prep<<<PACK_BLOCKS + WCVT_BLOCKS, 256, 0, stream>>>(adj, bits, Wmat, wbf);
  k_wh<<<BN/16, 256, 0, stream>>>(hmat, wbf, avec, VT, src, dst);
  k_attn<<<dim3(16, H, B), 256, 0, stream>>>(VT, src, dst, bits, out);
}